// Round 2
// baseline (753.837 us; speedup 1.0000x reference)
//
#include <hip/hip_runtime.h>
#include <hip/hip_bf16.h>

typedef __attribute__((ext_vector_type(8))) short short8;
typedef __attribute__((ext_vector_type(4))) short short4v;
typedef __attribute__((ext_vector_type(4))) float f32x4;

#define B_ 2
#define S_ 2048
#define E_ 2048
#define H_ 16
#define HKV_ 4
#define D_ 128
#define KV_DIM 512

__device__ __forceinline__ void gload_lds16(const void* g, void* l) {
  __builtin_amdgcn_global_load_lds(
      (const __attribute__((address_space(1))) unsigned int*)g,
      (__attribute__((address_space(3))) unsigned int*)l,
      16, 0, 0);
}

__device__ __forceinline__ short bf2s(float f) {
  __hip_bfloat16 h = __float2bfloat16(f);
  return *reinterpret_cast<short*>(&h);
}

// ---------------- fp32 -> bf16 convert ----------------
__global__ void cvt_f32_bf16(const float* __restrict__ in,
                             __hip_bfloat16* __restrict__ out, int n) {
  int i = (blockIdx.x * 256 + threadIdx.x) * 4;
  if (i >= n) return;
  const float4 v = *(const float4*)(in + i);
  short4v o;
  o.x = bf2s(v.x); o.y = bf2s(v.y); o.z = bf2s(v.z); o.w = bf2s(v.w);
  *(short4v*)(out + i) = o;
}

// ---------------- GEMM: C(M,N) = A(M,K) @ Bt(N,K)^T + bias ----------------
// m97 structure: 128x128 tile, BK=32, 256 threads = 4 waves (2x2), wave tile 64x64.
template <int OUT_F32>
__global__ __launch_bounds__(256) void gemm_bt(
    const __hip_bfloat16* __restrict__ A,
    const __hip_bfloat16* __restrict__ Bt,
    const float* __restrict__ bias,
    void* __restrict__ Cout,
    int M, int N, int K) {
  __shared__ __align__(16) __hip_bfloat16 As[128 * 32];
  __shared__ __align__(16) __hip_bfloat16 Bs[128 * 32];
  const int tid = threadIdx.x;
  const int w = tid >> 6;
  const int l = tid & 63;
  const int wr = w >> 1, wc = w & 1;
  const int bm = blockIdx.y, bn = blockIdx.x;
  const int ln = l & 15, lg = l >> 4;

  f32x4 acc[4][4] = {};

  const __hip_bfloat16* Ab = A + (size_t)bm * 128 * K;
  const __hip_bfloat16* Bb = Bt + (size_t)bn * 128 * K;
  const int r0 = tid >> 2;
  const int cc0 = (tid & 3) * 8;

  char* ldsA0 = (char*)As + w * 1024;
  char* ldsA1 = (char*)As + 4096 + w * 1024;
  char* ldsB0 = (char*)Bs + w * 1024;
  char* ldsB1 = (char*)Bs + 4096 + w * 1024;

  const int a_off = (wr * 64 + ln) * 32 + lg * 8;
  const int b_off = (wc * 64 + ln) * 32 + lg * 8;

  for (int k0 = 0; k0 < K; k0 += 32) {
    __syncthreads();
    gload_lds16(Ab + (size_t)r0 * K + k0 + cc0, ldsA0);
    gload_lds16(Ab + (size_t)(r0 + 64) * K + k0 + cc0, ldsA1);
    gload_lds16(Bb + (size_t)r0 * K + k0 + cc0, ldsB0);
    gload_lds16(Bb + (size_t)(r0 + 64) * K + k0 + cc0, ldsB1);
    __syncthreads();

    short8 af[4], bf[4];
#pragma unroll
    for (int mi = 0; mi < 4; mi++)
      af[mi] = *(const short8*)(As + a_off + mi * 16 * 32);
#pragma unroll
    for (int ni = 0; ni < 4; ni++)
      bf[ni] = *(const short8*)(Bs + b_off + ni * 16 * 32);
#pragma unroll
    for (int mi = 0; mi < 4; mi++)
#pragma unroll
      for (int ni = 0; ni < 4; ni++)
        acc[mi][ni] = __builtin_amdgcn_mfma_f32_16x16x32_bf16(
            af[mi], bf[ni], acc[mi][ni], 0, 0, 0);
  }

  const int gr = bm * 128 + wr * 64 + lg * 4;
  const int gc = bn * 128 + wc * 64 + ln;
#pragma unroll
  for (int mi = 0; mi < 4; mi++) {
#pragma unroll
    for (int ni = 0; ni < 4; ni++) {
      const int row = gr + mi * 16;
      const int col = gc + ni * 16;
      const float bv = bias[col];
#pragma unroll
      for (int j = 0; j < 4; j++) {
        float v = acc[mi][ni][j] + bv;
        if (OUT_F32)
          ((float*)Cout)[(size_t)(row + j) * N + col] = v;
        else
          ((__hip_bfloat16*)Cout)[(size_t)(row + j) * N + col] =
              __float2bfloat16(v);
      }
    }
  }
}

// ---------------- RoPE (NeoX half-split), in place on bf16 ----------------
__global__ void rope_kernel(__hip_bfloat16* __restrict__ X, int nheads, int ntok) {
  int idx = blockIdx.x * 256 + threadIdx.x;
  int total = ntok * nheads * 64;
  if (idx >= total) return;
  int i = idx & 63;
  int h = (idx >> 6) % nheads;
  int tok = idx / (64 * nheads);
  int s = tok & (S_ - 1);
  float invf = powf(10000.f, -(float)i / 64.f);
  float ang = (float)s * invf;
  float c = cosf(ang), sn = sinf(ang);
  __hip_bfloat16* p = X + (size_t)tok * (nheads * D_) + h * D_ + i;
  float x1 = __bfloat162float(p[0]);
  float x2 = __bfloat162float(p[64]);
  p[0] = __float2bfloat16(x1 * c - x2 * sn);
  p[64] = __float2bfloat16(x2 * c + x1 * sn);
}

// ---------------- V transpose: (b*S+s, kh*128+d) -> [((b*4+kh)*128+d)*S + s] --
__global__ void transpose_v(const __hip_bfloat16* __restrict__ V,
                            __hip_bfloat16* __restrict__ Vt) {
  int idx = blockIdx.x * 256 + threadIdx.x;
  int s = idx & (S_ - 1);
  int d = (idx >> 11) & (D_ - 1);
  int bk = idx >> 18;
  int b = bk >> 2, kh = bk & 3;
  Vt[idx] = V[(size_t)(b * S_ + s) * KV_DIM + kh * D_ + d];
}

// ---------------- causal flash attention ----------------
// grid (S/64, H, B), 256 threads = 4 waves, each wave owns 16 q-rows.
__global__ __launch_bounds__(256) void flash_attn(
    const __hip_bfloat16* __restrict__ Q,   // (B*S, 2048)
    const __hip_bfloat16* __restrict__ K,   // (B*S, 512)
    const __hip_bfloat16* __restrict__ Vt,  // ((b*4+kh)*128+d, S)
    __hip_bfloat16* __restrict__ O) {       // (B*S, 2048)
  __shared__ __align__(16) char lds[40960];
  char* Ks = lds;           // 64 x 128 bf16, xor-swizzled (16KB)
  char* Vs = lds + 16384;   // 128(d) x 64(kv) bf16, xor-swizzled (16KB)
  char* Ps = lds + 32768;   // per-wave 16 x 64 bf16, xor-swizzled (4 x 2KB)

  const int tid = threadIdx.x;
  const int w = tid >> 6, l = tid & 63;
  const int qb = blockIdx.x, h = blockIdx.y, b = blockIdx.z;
  const int kh = h >> 2;
  const int ln = l & 15, lg = l >> 4;

  // Q fragments: 16 rows x 128, kept in registers
  short8 qf[4];
  {
    const __hip_bfloat16* qp =
        Q + (size_t)(b * S_ + qb * 64 + w * 16 + ln) * E_ + h * D_ + lg * 8;
#pragma unroll
    for (int kd = 0; kd < 4; kd++) qf[kd] = *(const short8*)(qp + kd * 32);
  }

  f32x4 oacc[8] = {};
  float m_j[4], s_j[4];
#pragma unroll
  for (int j = 0; j < 4; j++) { m_j[j] = -__builtin_inff(); s_j[j] = 0.f; }

  const float SC = 0.08838834764831845f * 1.44269504088896f;  // scale*log2e

  const int nkv = qb + 1;
  for (int kvb = 0; kvb < nkv; kvb++) {
    __syncthreads();
    // stage K tile (64 rows x 128 d), 4 x 16B chunks per thread
#pragma unroll
    for (int i = 0; i < 4; i++) {
      int c = tid + i * 256;
      int r = c >> 4, cc = c & 15;
      short8 v = *(const short8*)(K + (size_t)(b * S_ + kvb * 64 + r) * KV_DIM +
                                  kh * D_ + cc * 8);
      int off = (r * 256 + cc * 16) ^ ((r & 7) << 4);
      *(short8*)(Ks + off) = v;
    }
    // stage V^T tile (128 d-rows x 64 kv)
#pragma unroll
    for (int i = 0; i < 4; i++) {
      int c = tid + i * 256;
      int r = c >> 3, cc = c & 7;
      short8 v = *(const short8*)(Vt + ((size_t)(b * HKV_ + kh) * D_ + r) * S_ +
                                  kvb * 64 + cc * 8);
      int off = (r * 128 + cc * 16) ^ ((r & 7) << 4);
      *(short8*)(Vs + off) = v;
    }
    __syncthreads();

    // QK^T: 16 MFMAs per wave -> 16x64 score tile
    f32x4 sc[4] = {};
#pragma unroll
    for (int ni = 0; ni < 4; ni++) {
      int row = ni * 16 + ln;
#pragma unroll
      for (int kd = 0; kd < 4; kd++) {
        int off = (row * 256 + kd * 64 + lg * 16) ^ ((row & 7) << 4);
        short8 kf = *(const short8*)(Ks + off);
        sc[ni] = __builtin_amdgcn_mfma_f32_16x16x32_bf16(qf[kd], kf, sc[ni], 0, 0, 0);
      }
    }

    if (kvb == qb) {  // diagonal block: causal mask
      int rowi = w * 16 + lg * 4;
#pragma unroll
      for (int ni = 0; ni < 4; ni++) {
        int coli = ni * 16 + ln;
#pragma unroll
        for (int j = 0; j < 4; j++)
          if (coli > rowi + j) sc[ni][j] = -__builtin_inff();
      }
    }

    // online softmax (rows live on 16-lane groups; reduce over cols)
    float f_j[4];
#pragma unroll
    for (int j = 0; j < 4; j++) {
      float v = fmaxf(fmaxf(sc[0][j], sc[1][j]), fmaxf(sc[2][j], sc[3][j]));
      v = fmaxf(v, __shfl_xor(v, 1));
      v = fmaxf(v, __shfl_xor(v, 2));
      v = fmaxf(v, __shfl_xor(v, 4));
      v = fmaxf(v, __shfl_xor(v, 8));
      float mn = fmaxf(m_j[j], v);
      f_j[j] = exp2f((m_j[j] - mn) * SC);
      m_j[j] = mn;
    }
    float p[4][4];
    float psum[4] = {0.f, 0.f, 0.f, 0.f};
#pragma unroll
    for (int ni = 0; ni < 4; ni++)
#pragma unroll
      for (int j = 0; j < 4; j++) {
        float pv = exp2f((sc[ni][j] - m_j[j]) * SC);
        p[ni][j] = pv;
        psum[j] += pv;
      }
#pragma unroll
    for (int j = 0; j < 4; j++) {
      float v = psum[j];
      v += __shfl_xor(v, 1);
      v += __shfl_xor(v, 2);
      v += __shfl_xor(v, 4);
      v += __shfl_xor(v, 8);
      s_j[j] = s_j[j] * f_j[j] + v;
    }
#pragma unroll
    for (int t = 0; t < 8; t++)
#pragma unroll
      for (int j = 0; j < 4; j++) oacc[t][j] *= f_j[j];

    // P -> LDS (bf16, swizzled), same-wave round trip
    {
      char* Pw = Ps + w * 2048;
#pragma unroll
      for (int ni = 0; ni < 4; ni++) {
        int colb = (ni * 16 + ln) * 2;
#pragma unroll
        for (int j = 0; j < 4; j++) {
          int prow = lg * 4 + j;
          int off = (prow * 128 + colb) ^ ((prow & 7) << 4);
          *(__hip_bfloat16*)(Pw + off) = __float2bfloat16(p[ni][j]);
        }
      }
      asm volatile("s_waitcnt lgkmcnt(0)" ::: "memory");
      __builtin_amdgcn_sched_barrier(0);
    }

    // PV: oacc[ni(d)] += P(16x64) @ V(64x16)
    {
      const char* Pw = Ps + w * 2048;
      short8 pa[2];
#pragma unroll
      for (int kc = 0; kc < 2; kc++) {
        int off = (ln * 128 + kc * 64 + lg * 16) ^ ((ln & 7) << 4);
        pa[kc] = *(const short8*)(Pw + off);
      }
#pragma unroll
      for (int ni = 0; ni < 8; ni++) {
        int vrow = ni * 16 + ln;
#pragma unroll
        for (int kc = 0; kc < 2; kc++) {
          int voff = (vrow * 128 + kc * 64 + lg * 16) ^ ((vrow & 7) << 4);
          short8 vf = *(const short8*)(Vs + voff);
          oacc[ni] = __builtin_amdgcn_mfma_f32_16x16x32_bf16(pa[kc], vf, oacc[ni], 0, 0, 0);
        }
      }
    }
  }

  // epilogue: normalize and store
  {
    float inv[4];
#pragma unroll
    for (int j = 0; j < 4; j++) inv[j] = 1.f / s_j[j];
    size_t rbase = (size_t)(b * S_ + qb * 64 + w * 16 + lg * 4) * E_ + h * D_ + ln;
#pragma unroll
    for (int ni = 0; ni < 8; ni++)
#pragma unroll
      for (int j = 0; j < 4; j++)
        O[rbase + (size_t)j * E_ + ni * 16] = __float2bfloat16(oacc[ni][j] * inv[j]);
  }
}

// ---------------- launch ----------------
extern "C" void kernel_launch(void* const* d_in, const int* in_sizes, int n_in,
                              void* d_out, int out_size, void* d_ws, size_t ws_size,
                              hipStream_t stream) {
  const float* x = (const float*)d_in[0];
  const float* wq = (const float*)d_in[1];
  const float* bq = (const float*)d_in[2];
  const float* wk = (const float*)d_in[3];
  const float* bk = (const float*)d_in[4];
  const float* wv = (const float*)d_in[5];
  const float* bv = (const float*)d_in[6];
  const float* wo = (const float*)d_in[7];
  const float* bo = (const float*)d_in[8];

  char* ws = (char*)d_ws;
  // layout (bytes, total 64 MB); xb is reused as attention output (Ab)
  __hip_bfloat16* xb  = (__hip_bfloat16*)(ws);                      // 16 MB
  __hip_bfloat16* Ab  = xb;                                         // alias
  __hip_bfloat16* Qb  = (__hip_bfloat16*)(ws + (16u << 20));        // 16 MB
  __hip_bfloat16* Kb  = (__hip_bfloat16*)(ws + (32u << 20));        // 4 MB
  __hip_bfloat16* Vb  = (__hip_bfloat16*)(ws + (36u << 20));        // 4 MB
  __hip_bfloat16* Vtb = (__hip_bfloat16*)(ws + (40u << 20));        // 4 MB
  __hip_bfloat16* wqb = (__hip_bfloat16*)(ws + (44u << 20));        // 8 MB
  __hip_bfloat16* wkb = (__hip_bfloat16*)(ws + (52u << 20));        // 2 MB
  __hip_bfloat16* wvb = (__hip_bfloat16*)(ws + (54u << 20));        // 2 MB
  __hip_bfloat16* wob = (__hip_bfloat16*)(ws + (56u << 20));        // 8 MB

  const int NX = B_ * S_ * E_;       // 8388608
  const int NWQ = E_ * E_;           // 4194304
  const int NWK = KV_DIM * E_;       // 1048576

  cvt_f32_bf16<<<NX / 1024, 256, 0, stream>>>(x, xb, NX);
  cvt_f32_bf16<<<NWQ / 1024, 256, 0, stream>>>(wq, wqb, NWQ);
  cvt_f32_bf16<<<NWK / 1024, 256, 0, stream>>>(wk, wkb, NWK);
  cvt_f32_bf16<<<NWK / 1024, 256, 0, stream>>>(wv, wvb, NWK);
  cvt_f32_bf16<<<NWQ / 1024, 256, 0, stream>>>(wo, wob, NWQ);

  gemm_bt<0><<<dim3(16, 32), 256, 0, stream>>>(xb, wqb, bq, Qb, 4096, 2048, 2048);
  gemm_bt<0><<<dim3(4, 32), 256, 0, stream>>>(xb, wkb, bk, Kb, 4096, 512, 2048);
  gemm_bt<0><<<dim3(4, 32), 256, 0, stream>>>(xb, wvb, bv, Vb, 4096, 512, 2048);

  rope_kernel<<<(4096 * 16 * 64) / 256, 256, 0, stream>>>(Qb, 16, 4096);
  rope_kernel<<<(4096 * 4 * 64) / 256, 256, 0, stream>>>(Kb, 4, 4096);

  transpose_v<<<(B_ * HKV_ * D_ * S_) / 256, 256, 0, stream>>>(Vb, Vtb);

  flash_attn<<<dim3(32, 16, 2), 256, 0, stream>>>(Qb, Kb, Vtb, Ab);

  gemm_bt<1><<<dim3(16, 32), 256, 0, stream>>>(Ab, wob, bo, d_out, 4096, 2048, 2048);
}